// Round 6
// baseline (1771.444 us; speedup 1.0000x reference)
//
#include <hip/hip_runtime.h>
#include <hip/hip_bf16.h>
#include <hip/hip_fp16.h>
#include <cstdint>
#include <cstddef>

// ---------------------------------------------------------------------------
// GCN: 3x GCNConv (symmetric norm, self loops) + global_mean_pool + MLP head.
// Factorization: norm = dinv[s]*dinv[d]  =>  per layer:
//   g = dinv .* (X @ W)        (GEMM, epilogue scale, stored FP16)
//   h'[d] = act(dinv[d]*(g[d] + sum_{e: dst=d} g[src_e]) + b)   (f32 accum)
// batch is sorted -> pooling via binary search, no atomics.
//
// R1: k_gemm unroll capped (was spilling ~5 GB scratch traffic).
// R2: k_agg edge loop unrolled -> only +8%: gather is BW-bound, not latency.
// R3: g stored fp16 (gather operand only; accum f32). absmax 6.1e-5.
// R4: CSR build as 2-level LDS-binned counting sort (atomics 6.4M -> 611K).
// R5: k_agg split into 3 feature-phase LAUNCHES (features l+32*ph). Evidence:
//     agg pinned at ~3.8 TB/s beyond-L2 with 41% L2 hit on a 38.4 MB table
//     (FETCH 751 MB = 0.59 x 1.27 GB logical, 64B granule). Phase table is
//     12.8 MB -> higher hit rate; separate launches align phases device-wide.
// ---------------------------------------------------------------------------

#define H96 96

static constexpr int NB_SHIFT = 8;         // bucket = dst >> 8
static constexpr int DPB = 1 << NB_SHIFT;  // 256 dsts per bucket
static constexpr int NBMAX = 800;          // max buckets (N <= 204800)
static constexpr int EPB = 8192;           // edges per binscatter block

// ---------------- CSR build: two-level counting sort ----------------

__global__ __launch_bounds__(256, 4) void k_binscatter(
    const int* __restrict__ src, const int* __restrict__ dst, int E, int nb,
    int cap, int* __restrict__ gfill, unsigned* __restrict__ pairs) {
    __shared__ int cnt[NBMAX];
    const int tid = threadIdx.x;
    for (int b = tid; b < nb; b += 256) cnt[b] = 0;
    __syncthreads();

    const int base = blockIdx.x * EPB;
    int s[32], d[32];
#pragma unroll
    for (int q = 0; q < 32; ++q) {
        const int idx = base + q * 256 + tid;
        if (idx < E) {
            s[q] = src[idx];
            d[q] = dst[idx];
            atomicAdd(&cnt[d[q] >> NB_SHIFT], 1);
        } else {
            d[q] = -1;
        }
    }
    __syncthreads();
    // reserve a contiguous slice of each bucket region for this block
    for (int b = tid; b < nb; b += 256) {
        const int c = cnt[b];
        cnt[b] = (c > 0) ? atomicAdd(&gfill[b], c) : 0;  // cnt becomes cursor
    }
    __syncthreads();
#pragma unroll
    for (int q = 0; q < 32; ++q) {
        if (d[q] >= 0) {
            const int b = d[q] >> NB_SHIFT;
            const int p = atomicAdd(&cnt[b], 1);  // LDS rank
            if (p < cap)
                pairs[(size_t)b * cap + p] =
                    (unsigned)(s[q] & 0xFFFFFF) | ((unsigned)(d[q] & (DPB - 1)) << 24);
        }
    }
}

__global__ void k_bstart(const int* __restrict__ gfill, int* __restrict__ bstart, int nb) {
    __shared__ int sm[1024];
    const int tid = threadIdx.x;
    const int v = (tid < nb) ? gfill[tid] : 0;
    sm[tid] = v;
    __syncthreads();
    for (int o = 1; o < 1024; o <<= 1) {
        const int t = (tid >= o) ? sm[tid - o] : 0;
        __syncthreads();
        sm[tid] += t;
        __syncthreads();
    }
    if (tid < nb) bstart[tid] = sm[tid] - v;  // exclusive
    if (tid == 0) bstart[nb] = sm[1023];      // total
}

// One block per bucket: histogram 256 local dsts, scan, write rowptr/dinv,
// then scatter srcs into csr with LDS-atomic ranks. No global atomics.
__global__ __launch_bounds__(256) void k_build2(
    const unsigned* __restrict__ pairs, const int* __restrict__ gfill,
    const int* __restrict__ bstart, int cap, int* __restrict__ rowptr,
    float* __restrict__ dinv, int* __restrict__ csr, int N, int E) {
    __shared__ int cnt2[DPB];
    __shared__ int off2[DPB];
    const int b = blockIdx.x, tid = threadIdx.x;
    const int m = min(gfill[b], cap);
    const unsigned* pb = pairs + (size_t)b * cap;

    cnt2[tid] = 0;
    __syncthreads();
    for (int i = tid; i < m; i += 256) atomicAdd(&cnt2[pb[i] >> 24], 1);
    __syncthreads();

    const int v = cnt2[tid];  // degree of local dst `tid`
    off2[tid] = v;
    __syncthreads();
    for (int o = 1; o < 256; o <<= 1) {
        const int t = (tid >= o) ? off2[tid - o] : 0;
        __syncthreads();
        off2[tid] += t;
        __syncthreads();
    }
    const int excl = off2[tid] - v;
    const int base = bstart[b];
    const int dg = (b << NB_SHIFT) + tid;
    if (dg < N) {
        rowptr[dg] = base + excl;
        dinv[dg] = 1.0f / sqrtf((float)(v + 1));  // +1 self loop
    }
    if (b == 0 && tid == 0) rowptr[N] = E;
    __syncthreads();
    cnt2[tid] = excl;  // becomes cursor
    __syncthreads();
    for (int i = tid; i < m; i += 256) {
        const unsigned pk = pb[i];
        const int pos = base + atomicAdd(&cnt2[pk >> 24], 1);
        csr[pos] = (int)(pk & 0xFFFFFF);
    }
}

// ---------------- GEMM: Out[n][j] = fp16( dinv[n] * sum_k X[n][k] W[k][j] ) --
// Block: 384 threads, 64 nodes x 96 cols per block. Thread: 4 nodes x 4 cols.
// K-chunked LDS staging. Unrolling deliberately capped (R1: spills).

template <int K, int KC>
__global__ __launch_bounds__(384, 2) void k_gemm(const float* __restrict__ X,
                                                 const float* __restrict__ W,
                                                 const float* __restrict__ dinv,
                                                 __half* __restrict__ Out) {
    __shared__ float xs[64][KC + 4];
    __shared__ float ws[KC][H96];
    const int tid = threadIdx.x;
    const int nb = blockIdx.x * 64;
    const int tc = tid % 24;  // col group: j0 = tc*4
    const int tn = tid / 24;  // node group 0..15: n0 = tn*4

    float acc[4][4];
#pragma unroll
    for (int i = 0; i < 4; ++i)
#pragma unroll
        for (int c = 0; c < 4; ++c) acc[i][c] = 0.0f;

#pragma unroll 1
    for (int kc = 0; kc < K / KC; ++kc) {
        // stage X tile (64 x KC)
#pragma unroll 1
        for (int idx = tid; idx < 64 * (KC / 4); idx += 384) {
            int row = idx / (KC / 4), kq = idx % (KC / 4);
            const float4 v = *(const float4*)&X[(size_t)(nb + row) * K + kc * KC + kq * 4];
            *(float4*)&xs[row][kq * 4] = v;
        }
        // stage W tile (KC x 96)
#pragma unroll 1
        for (int idx = tid; idx < KC * 24; idx += 384) {
            int k = idx / 24, jq = idx % 24;
            const float4 v = *(const float4*)&W[(size_t)(kc * KC + k) * H96 + jq * 4];
            *(float4*)&ws[k][jq * 4] = v;
        }
        __syncthreads();

#pragma unroll 2
        for (int k = 0; k < KC; k += 4) {
            float4 wv[4];
#pragma unroll
            for (int kk = 0; kk < 4; ++kk) wv[kk] = *(float4*)&ws[k + kk][tc * 4];
#pragma unroll
            for (int i = 0; i < 4; ++i) {
                const float4 xq = *(float4*)&xs[tn * 4 + i][k];
                acc[i][0] = fmaf(xq.x, wv[0].x, acc[i][0]);
                acc[i][1] = fmaf(xq.x, wv[0].y, acc[i][1]);
                acc[i][2] = fmaf(xq.x, wv[0].z, acc[i][2]);
                acc[i][3] = fmaf(xq.x, wv[0].w, acc[i][3]);
                acc[i][0] = fmaf(xq.y, wv[1].x, acc[i][0]);
                acc[i][1] = fmaf(xq.y, wv[1].y, acc[i][1]);
                acc[i][2] = fmaf(xq.y, wv[1].z, acc[i][2]);
                acc[i][3] = fmaf(xq.y, wv[1].w, acc[i][3]);
                acc[i][0] = fmaf(xq.z, wv[2].x, acc[i][0]);
                acc[i][1] = fmaf(xq.z, wv[2].y, acc[i][1]);
                acc[i][2] = fmaf(xq.z, wv[2].z, acc[i][2]);
                acc[i][3] = fmaf(xq.z, wv[2].w, acc[i][3]);
                acc[i][0] = fmaf(xq.w, wv[3].x, acc[i][0]);
                acc[i][1] = fmaf(xq.w, wv[3].y, acc[i][1]);
                acc[i][2] = fmaf(xq.w, wv[3].z, acc[i][2]);
                acc[i][3] = fmaf(xq.w, wv[3].w, acc[i][3]);
            }
        }
        __syncthreads();
    }

    const int n0 = nb + tn * 4;
#pragma unroll
    for (int i = 0; i < 4; ++i) {
        const float sc = dinv[n0 + i];
        union { __half h[4]; uint2 u; } pk;
#pragma unroll
        for (int c = 0; c < 4; ++c) pk.h[c] = __float2half(acc[i][c] * sc);
        *(uint2*)&Out[(size_t)(n0 + i) * H96 + tc * 4] = pk.u;
    }
}

// ---------------- Aggregation (one feature-phase): ---------------------------
// h[d][fo+l'] = act(dinv[d]*(g[d][fo+l'] + sum g[src][fo+l']) + b[fo+l'])
// One wave per node; halves process alternating edges; lane covers ONE feature
// (fo + lane&31) -> each gathered row touches a single 64B line per phase.
// 8-edge batches keep 8 loads in flight per half.

__global__ void k_agg(const __half* __restrict__ g, const int* __restrict__ rowptr,
                      const int* __restrict__ csr, const float* __restrict__ dinv,
                      const float* __restrict__ bias, float* __restrict__ hout,
                      int N, int RELU, int fo) {
    const int d = (blockIdx.x * blockDim.x + threadIdx.x) >> 6;  // node = global wave
    if (d >= N) return;
    const int lane = threadIdx.x & 63;
    const int half = lane >> 5;
    const int l = (lane & 31) + fo;  // global feature index

    float a0 = (half == 0) ? __half2float(g[(size_t)d * H96 + l]) : 0.0f;  // self loop
    float a1 = 0.f, a2 = 0.f, a3 = 0.f;
    float a4 = 0.f, a5 = 0.f, a6 = 0.f, a7 = 0.f;

    const int r0 = rowptr[d], r1 = rowptr[d + 1];
    int e = r0 + half;
#pragma unroll 1
    for (; e + 14 < r1; e += 16) {
        const int s0 = csr[e];
        const int s1 = csr[e + 2];
        const int s2 = csr[e + 4];
        const int s3 = csr[e + 6];
        const int s4 = csr[e + 8];
        const int s5 = csr[e + 10];
        const int s6 = csr[e + 12];
        const int s7 = csr[e + 14];
        const float v0 = __half2float(g[(size_t)s0 * H96 + l]);
        const float v1 = __half2float(g[(size_t)s1 * H96 + l]);
        const float v2 = __half2float(g[(size_t)s2 * H96 + l]);
        const float v3 = __half2float(g[(size_t)s3 * H96 + l]);
        const float v4 = __half2float(g[(size_t)s4 * H96 + l]);
        const float v5 = __half2float(g[(size_t)s5 * H96 + l]);
        const float v6 = __half2float(g[(size_t)s6 * H96 + l]);
        const float v7 = __half2float(g[(size_t)s7 * H96 + l]);
        a0 += v0; a1 += v1; a2 += v2; a3 += v3;
        a4 += v4; a5 += v5; a6 += v6; a7 += v7;
    }
#pragma unroll 1
    for (; e < r1; e += 2) {
        a0 += __half2float(g[(size_t)csr[e] * H96 + l]);
    }
    float s = ((a0 + a1) + (a2 + a3)) + ((a4 + a5) + (a6 + a7));
    s += __shfl_xor(s, 32);

    if (half == 0) {
        float v = dinv[d] * s + bias[l];
        if (RELU) v = fmaxf(v, 0.f);
        hout[(size_t)d * H96 + l] = v;
    }
}

// ---------------- Pooling (batch sorted) + MLP head --------------------------

__global__ void k_pool_head(const float* __restrict__ h, const int* __restrict__ batch,
                            const float* __restrict__ Wl1, const float* __restrict__ bl1,
                            const float* __restrict__ Wl2, const float* __restrict__ bl2,
                            float* __restrict__ out, int N) {
    const int gph = blockIdx.x;
    const int tid = threadIdx.x;  // 128 threads

    // lower_bound over sorted batch
    int lo = 0, hi = N;
    while (lo < hi) { int mid = (lo + hi) >> 1; if (batch[mid] < gph) lo = mid + 1; else hi = mid; }
    const int seg_lo = lo;
    lo = seg_lo; hi = N;
    while (lo < hi) { int mid = (lo + hi) >> 1; if (batch[mid] < gph + 1) lo = mid + 1; else hi = mid; }
    const int seg_hi = lo;

    __shared__ float pl[H96];
    __shared__ float prod[H96];
    const float inv_cnt = 1.0f / (float)max(seg_hi - seg_lo, 1);
    if (tid < H96) {
        float s = 0.0f;
        for (int n = seg_lo; n < seg_hi; ++n) s += h[(size_t)n * H96 + tid];
        pl[tid] = s * inv_cnt;
    }
    __syncthreads();
    if (tid < H96) {
        float hd = bl1[tid];
        for (int k = 0; k < H96; ++k) hd = fmaf(pl[k], Wl1[k * H96 + tid], hd);
        hd = fmaxf(hd, 0.0f);
        prod[tid] = hd * Wl2[tid];
    }
    __syncthreads();
    if (tid < 32) {
        float v = prod[tid] + prod[tid + 32] + prod[tid + 64];
        for (int o = 16; o; o >>= 1) v += __shfl_down(v, o);
        if (tid == 0) out[gph] = v + bl2[0];
    }
}

// ---------------- launch -----------------------------------------------------

extern "C" void kernel_launch(void* const* d_in, const int* in_sizes, int n_in,
                              void* d_out, int out_size, void* d_ws, size_t ws_size,
                              hipStream_t stream) {
    const float* x   = (const float*)d_in[0];
    const float* W1  = (const float*)d_in[1];
    const float* b1  = (const float*)d_in[2];
    const float* W2  = (const float*)d_in[3];
    const float* b2  = (const float*)d_in[4];
    const float* W3  = (const float*)d_in[5];
    const float* b3  = (const float*)d_in[6];
    const float* Wl1 = (const float*)d_in[7];
    const float* bl1 = (const float*)d_in[8];
    const float* Wl2 = (const float*)d_in[9];
    const float* bl2 = (const float*)d_in[10];
    const int*   ei  = (const int*)d_in[11];
    const int*   bat = (const int*)d_in[12];

    const int N = in_sizes[0] / 128;
    const int E = in_sizes[11] / 2;
    const int G = out_size;  // [G,1]
    const int* src = ei;
    const int* dst = ei + E;

    const int nb = (N + DPB - 1) >> NB_SHIFT;            // buckets (782)
    const int avg = E / nb;
    const int cap = (avg + (avg >> 3) + 1024 + 255) & ~255;  // ~avg+13%+1K

    char* wsb = (char*)d_ws;
    size_t off = 0;
    auto alloc = [&](size_t bytes) {
        void* p = wsb + off;
        off += (bytes + 255) & ~(size_t)255;
        return p;
    };
    __half*   g      = (__half*)alloc((size_t)N * H96 * 2);
    float*    h      = (float*)alloc((size_t)N * H96 * 4);
    int*      csr    = (int*)alloc((size_t)E * 4);
    int*      rowptr = (int*)alloc((size_t)(N + 1) * 4);
    float*    dinv   = (float*)alloc((size_t)N * 4);
    unsigned* pairs  = (unsigned*)alloc((size_t)nb * cap * 4);
    int*      gfill  = (int*)alloc((size_t)(nb + 1) * 4);
    int*      bstart = (int*)alloc((size_t)(nb + 1) * 4);

    hipMemsetAsync(gfill, 0, (size_t)nb * 4, stream);

    // CSR build: 2-level counting sort (R4)
    const int bs_blocks = (E + EPB - 1) / EPB;
    k_binscatter<<<bs_blocks, 256, 0, stream>>>(src, dst, E, nb, cap, gfill, pairs);
    k_bstart<<<1, 1024, 0, stream>>>(gfill, bstart, nb);
    k_build2<<<nb, 256, 0, stream>>>(pairs, gfill, bstart, cap, rowptr, dinv, csr, N, E);

    const int gemm_blocks = N / 64;          // N = 200000 -> 3125
    const int agg_blocks = (N + 3) / 4;      // 4 nodes (waves) per 256-thr block

    // layer 1
    k_gemm<128, 64><<<gemm_blocks, 384, 0, stream>>>(x, W1, dinv, g);
    for (int ph = 0; ph < 3; ++ph)
        k_agg<<<agg_blocks, 256, 0, stream>>>(g, rowptr, csr, dinv, b1, h, N, 1, ph * 32);
    // layer 2
    k_gemm<96, 48><<<gemm_blocks, 384, 0, stream>>>(h, W2, dinv, g);
    for (int ph = 0; ph < 3; ++ph)
        k_agg<<<agg_blocks, 256, 0, stream>>>(g, rowptr, csr, dinv, b2, h, N, 1, ph * 32);
    // layer 3
    k_gemm<96, 48><<<gemm_blocks, 384, 0, stream>>>(h, W3, dinv, g);
    for (int ph = 0; ph < 3; ++ph)
        k_agg<<<agg_blocks, 256, 0, stream>>>(g, rowptr, csr, dinv, b3, h, N, 0, ph * 32);

    // pool + head
    k_pool_head<<<G, 128, 0, stream>>>(h, bat, Wl1, bl1, Wl2, bl2, (float*)d_out, N);
}

// Round 7
// 906.896 us; speedup vs baseline: 1.9533x; 1.9533x over previous
//
#include <hip/hip_runtime.h>
#include <hip/hip_bf16.h>
#include <hip/hip_fp16.h>
#include <cstdint>
#include <cstddef>
#include <type_traits>

// ---------------------------------------------------------------------------
// GCN: 3x GCNConv (symmetric norm, self loops) + global_mean_pool + MLP head.
// Factorization: norm = dinv[s]*dinv[d]  =>  per layer:
//   g = dinv .* (X @ W)        (MFMA GEMM, epilogue scale, stored FP16)
//   h'[d] = act(dinv[d]*(g[d] + sum_{e: dst=d} g[src_e]) + b)   (f32 accum,
//                                                               stored FP16)
// batch is sorted -> pooling via binary search, no atomics.
//
// R1: fp32 GEMM unroll capped (was spilling ~5 GB scratch traffic).
// R2: k_agg edge loop unrolled -> only +8%: gather is BW-bound, not latency.
// R3: g stored fp16 (gather operand only; accum f32). absmax 6.1e-5.
// R4: CSR build as 2-level LDS-binned counting sort (atomics 6.4M -> 611K).
// R5 REVERTED: 3 feature-phase agg launches made L2 hit WORSE (18% vs 41%,
//     FETCH 1.12GB vs 751MB/layer). Single-pass 192B-row gather at 3.84 TB/s
//     is the random-access fabric floor (ILP-insensitive per R2).
// R6: GEMMs moved to MFMA (16x16x32 f16, f32 accum). A/B fragments use the
//     same slot->k bijection (correct for any HW k-permutation); C/D mapping
//     col=lane&15,row=(lane>>4)*4+reg [HW-verified]. W^T staged in LDS fp16
//     (+8 pad). h stored fp16 (one buffer reused; pool reads fp16).
// ---------------------------------------------------------------------------

#define H96 96

typedef _Float16 f16x8 __attribute__((ext_vector_type(8)));
typedef float f32x4 __attribute__((ext_vector_type(4)));

static constexpr int NB_SHIFT = 8;         // bucket = dst >> 8
static constexpr int DPB = 1 << NB_SHIFT;  // 256 dsts per bucket
static constexpr int NBMAX = 800;          // max buckets (N <= 204800)
static constexpr int EPB = 8192;           // edges per binscatter block

// ---------------- CSR build: two-level counting sort ----------------

__global__ __launch_bounds__(256, 4) void k_binscatter(
    const int* __restrict__ src, const int* __restrict__ dst, int E, int nb,
    int cap, int* __restrict__ gfill, unsigned* __restrict__ pairs) {
    __shared__ int cnt[NBMAX];
    const int tid = threadIdx.x;
    for (int b = tid; b < nb; b += 256) cnt[b] = 0;
    __syncthreads();

    const int base = blockIdx.x * EPB;
    int s[32], d[32];
#pragma unroll
    for (int q = 0; q < 32; ++q) {
        const int idx = base + q * 256 + tid;
        if (idx < E) {
            s[q] = src[idx];
            d[q] = dst[idx];
            atomicAdd(&cnt[d[q] >> NB_SHIFT], 1);
        } else {
            d[q] = -1;
        }
    }
    __syncthreads();
    // reserve a contiguous slice of each bucket region for this block
    for (int b = tid; b < nb; b += 256) {
        const int c = cnt[b];
        cnt[b] = (c > 0) ? atomicAdd(&gfill[b], c) : 0;  // cnt becomes cursor
    }
    __syncthreads();
#pragma unroll
    for (int q = 0; q < 32; ++q) {
        if (d[q] >= 0) {
            const int b = d[q] >> NB_SHIFT;
            const int p = atomicAdd(&cnt[b], 1);  // LDS rank
            if (p < cap)
                pairs[(size_t)b * cap + p] =
                    (unsigned)(s[q] & 0xFFFFFF) | ((unsigned)(d[q] & (DPB - 1)) << 24);
        }
    }
}

__global__ void k_bstart(const int* __restrict__ gfill, int* __restrict__ bstart, int nb) {
    __shared__ int sm[1024];
    const int tid = threadIdx.x;
    const int v = (tid < nb) ? gfill[tid] : 0;
    sm[tid] = v;
    __syncthreads();
    for (int o = 1; o < 1024; o <<= 1) {
        const int t = (tid >= o) ? sm[tid - o] : 0;
        __syncthreads();
        sm[tid] += t;
        __syncthreads();
    }
    if (tid < nb) bstart[tid] = sm[tid] - v;  // exclusive
    if (tid == 0) bstart[nb] = sm[1023];      // total
}

// One block per bucket: histogram 256 local dsts, scan, write rowptr/dinv,
// then scatter srcs into csr with LDS-atomic ranks. No global atomics.
__global__ __launch_bounds__(256) void k_build2(
    const unsigned* __restrict__ pairs, const int* __restrict__ gfill,
    const int* __restrict__ bstart, int cap, int* __restrict__ rowptr,
    float* __restrict__ dinv, int* __restrict__ csr, int N, int E) {
    __shared__ int cnt2[DPB];
    __shared__ int off2[DPB];
    const int b = blockIdx.x, tid = threadIdx.x;
    const int m = min(gfill[b], cap);
    const unsigned* pb = pairs + (size_t)b * cap;

    cnt2[tid] = 0;
    __syncthreads();
    for (int i = tid; i < m; i += 256) atomicAdd(&cnt2[pb[i] >> 24], 1);
    __syncthreads();

    const int v = cnt2[tid];  // degree of local dst `tid`
    off2[tid] = v;
    __syncthreads();
    for (int o = 1; o < 256; o <<= 1) {
        const int t = (tid >= o) ? off2[tid - o] : 0;
        __syncthreads();
        off2[tid] += t;
        __syncthreads();
    }
    const int excl = off2[tid] - v;
    const int base = bstart[b];
    const int dg = (b << NB_SHIFT) + tid;
    if (dg < N) {
        rowptr[dg] = base + excl;
        dinv[dg] = 1.0f / sqrtf((float)(v + 1));  // +1 self loop
    }
    if (b == 0 && tid == 0) rowptr[N] = E;
    __syncthreads();
    cnt2[tid] = excl;  // becomes cursor
    __syncthreads();
    for (int i = tid; i < m; i += 256) {
        const unsigned pk = pb[i];
        const int pos = base + atomicAdd(&cnt2[pk >> 24], 1);
        csr[pos] = (int)(pk & 0xFFFFFF);
    }
}

// ---------------- MFMA GEMM: Out[n][j] = fp16( dinv[n] * X[n][:] @ W[:][j] ) -
// 256 threads = 4 waves; block tile 64 rows x 96 cols; wave tile 16 x 96
// (6 col-blocks of 16). K in steps of 32 via mfma_f32_16x16x32_f16 (f32 acc).
// A-frag: lane holds row=l&15, k-slots (l>>4)*8..+7 (16B load).
// B-frag: same slot->k bijection from LDS W^T -> correct for any HW k-perm.
// C/D: col=lane&15, row=(lane>>4)*4+reg.

template <int K, typename AT>
__global__ __launch_bounds__(256) void k_gemm_mfma(const AT* __restrict__ X,
                                                   const float* __restrict__ W,
                                                   const float* __restrict__ dinv,
                                                   __half* __restrict__ Out) {
    __shared__ _Float16 wt[H96][K + 8];  // W transposed, fp16, padded
    const int tid = threadIdx.x;
    const int l = tid & 63;
    const int w = tid >> 6;

    // stage W^T (K x 96 f32 -> [j][k] fp16)
    for (int idx = tid; idx < K * H96; idx += 256) {
        const int k = idx / H96, j = idx % H96;
        wt[j][k] = (_Float16)W[idx];
    }
    __syncthreads();

    const int g16 = l >> 4;  // k-slot group 0..3
    const int rl = l & 15;   // row (A) / col (B) within 16
    const size_t n0 = (size_t)blockIdx.x * 64 + w * 16;

    f32x4 acc[6];
#pragma unroll
    for (int c = 0; c < 6; ++c) acc[c] = (f32x4){0.f, 0.f, 0.f, 0.f};

#pragma unroll
    for (int kk = 0; kk < K / 32; ++kk) {
        const int k0 = kk * 32 + g16 * 8;
        f16x8 a;
        if constexpr (std::is_same<AT, float>::value) {
            const float* xr = X + (n0 + rl) * K + k0;
            const float4 lo = *(const float4*)xr;
            const float4 hi = *(const float4*)(xr + 4);
            a[0] = (_Float16)lo.x; a[1] = (_Float16)lo.y;
            a[2] = (_Float16)lo.z; a[3] = (_Float16)lo.w;
            a[4] = (_Float16)hi.x; a[5] = (_Float16)hi.y;
            a[6] = (_Float16)hi.z; a[7] = (_Float16)hi.w;
        } else {
            a = *(const f16x8*)((const _Float16*)X + (n0 + rl) * K + k0);
        }
#pragma unroll
        for (int c = 0; c < 6; ++c) {
            const f16x8 b = *(const f16x8*)&wt[c * 16 + rl][k0];
            acc[c] = __builtin_amdgcn_mfma_f32_16x16x32_f16(a, b, acc[c], 0, 0, 0);
        }
    }

    const int r0 = g16 * 4;
    float dv[4];
#pragma unroll
    for (int r = 0; r < 4; ++r) dv[r] = dinv[n0 + r0 + r];
#pragma unroll
    for (int c = 0; c < 6; ++c)
#pragma unroll
        for (int r = 0; r < 4; ++r)
            Out[(n0 + r0 + r) * H96 + c * 16 + rl] = __float2half(acc[c][r] * dv[r]);
}

// ---------------- Aggregation: h[d] = act(dinv[d]*(g[d]+sum g[src]) + b) -----
// One wave (64 lanes) per node; halves (32 lanes) process alternating edges;
// each lane owns features {l, l+32, l+64}. Edge loop unrolled x4 (R2). Gather
// operand fp16 (R3), accumulation f32, output fp16 (R6).

__global__ void k_agg(const __half* __restrict__ g, const int* __restrict__ rowptr,
                      const int* __restrict__ csr, const float* __restrict__ dinv,
                      const float* __restrict__ bias, __half* __restrict__ hout,
                      int N, int RELU) {
    const int d = (blockIdx.x * blockDim.x + threadIdx.x) >> 6;  // node = global wave
    if (d >= N) return;
    const int lane = threadIdx.x & 63;
    const int half = lane >> 5;
    const int l = lane & 31;

    float a0, a1, a2;
    if (half == 0) {  // self loop contribution (counted once)
        const __half* gr = g + (size_t)d * H96;
        a0 = __half2float(gr[l]);
        a1 = __half2float(gr[l + 32]);
        a2 = __half2float(gr[l + 64]);
    } else {
        a0 = a1 = a2 = 0.0f;
    }
    float b0 = 0.f, b1 = 0.f, b2 = 0.f;
    float c0 = 0.f, c1 = 0.f, c2 = 0.f;
    float e0 = 0.f, e1 = 0.f, e2 = 0.f;

    const int r0 = rowptr[d], r1 = rowptr[d + 1];
    int e = r0 + half;
#pragma unroll 1
    for (; e + 6 < r1; e += 8) {
        const int s0 = csr[e];
        const int s1 = csr[e + 2];
        const int s2 = csr[e + 4];
        const int s3 = csr[e + 6];
        const __half* g0 = g + (size_t)s0 * H96;
        const __half* g1 = g + (size_t)s1 * H96;
        const __half* g2 = g + (size_t)s2 * H96;
        const __half* g3 = g + (size_t)s3 * H96;
        const float v00 = __half2float(g0[l]);
        const float v01 = __half2float(g0[l + 32]);
        const float v02 = __half2float(g0[l + 64]);
        const float v10 = __half2float(g1[l]);
        const float v11 = __half2float(g1[l + 32]);
        const float v12 = __half2float(g1[l + 64]);
        const float v20 = __half2float(g2[l]);
        const float v21 = __half2float(g2[l + 32]);
        const float v22 = __half2float(g2[l + 64]);
        const float v30 = __half2float(g3[l]);
        const float v31 = __half2float(g3[l + 32]);
        const float v32 = __half2float(g3[l + 64]);
        a0 += v00; a1 += v01; a2 += v02;
        b0 += v10; b1 += v11; b2 += v12;
        c0 += v20; c1 += v21; c2 += v22;
        e0 += v30; e1 += v31; e2 += v32;
    }
#pragma unroll 1
    for (; e < r1; e += 2) {
        const int s = csr[e];
        const __half* gs = g + (size_t)s * H96;
        a0 += __half2float(gs[l]);
        a1 += __half2float(gs[l + 32]);
        a2 += __half2float(gs[l + 64]);
    }
    a0 += (b0 + c0) + e0;
    a1 += (b1 + c1) + e1;
    a2 += (b2 + c2) + e2;

    a0 += __shfl_xor(a0, 32);
    a1 += __shfl_xor(a1, 32);
    a2 += __shfl_xor(a2, 32);

    if (half == 0) {
        const float sc = dinv[d];
        float v0 = sc * a0 + bias[l];
        float v1 = sc * a1 + bias[l + 32];
        float v2 = sc * a2 + bias[l + 64];
        if (RELU) { v0 = fmaxf(v0, 0.f); v1 = fmaxf(v1, 0.f); v2 = fmaxf(v2, 0.f); }
        __half* ho = hout + (size_t)d * H96;
        ho[l] = __float2half(v0);
        ho[l + 32] = __float2half(v1);
        ho[l + 64] = __float2half(v2);
    }
}

// ---------------- Pooling (batch sorted) + MLP head --------------------------

__global__ void k_pool_head(const __half* __restrict__ h, const int* __restrict__ batch,
                            const float* __restrict__ Wl1, const float* __restrict__ bl1,
                            const float* __restrict__ Wl2, const float* __restrict__ bl2,
                            float* __restrict__ out, int N) {
    const int gph = blockIdx.x;
    const int tid = threadIdx.x;  // 128 threads

    // lower_bound over sorted batch
    int lo = 0, hi = N;
    while (lo < hi) { int mid = (lo + hi) >> 1; if (batch[mid] < gph) lo = mid + 1; else hi = mid; }
    const int seg_lo = lo;
    lo = seg_lo; hi = N;
    while (lo < hi) { int mid = (lo + hi) >> 1; if (batch[mid] < gph + 1) lo = mid + 1; else hi = mid; }
    const int seg_hi = lo;

    __shared__ float pl[H96];
    __shared__ float prod[H96];
    const float inv_cnt = 1.0f / (float)max(seg_hi - seg_lo, 1);
    if (tid < H96) {
        float s = 0.0f;
        for (int n = seg_lo; n < seg_hi; ++n) s += __half2float(h[(size_t)n * H96 + tid]);
        pl[tid] = s * inv_cnt;
    }
    __syncthreads();
    if (tid < H96) {
        float hd = bl1[tid];
        for (int k = 0; k < H96; ++k) hd = fmaf(pl[k], Wl1[k * H96 + tid], hd);
        hd = fmaxf(hd, 0.0f);
        prod[tid] = hd * Wl2[tid];
    }
    __syncthreads();
    if (tid < 32) {
        float v = prod[tid] + prod[tid + 32] + prod[tid + 64];
        for (int o = 16; o; o >>= 1) v += __shfl_down(v, o);
        if (tid == 0) out[gph] = v + bl2[0];
    }
}

// ---------------- launch -----------------------------------------------------

extern "C" void kernel_launch(void* const* d_in, const int* in_sizes, int n_in,
                              void* d_out, int out_size, void* d_ws, size_t ws_size,
                              hipStream_t stream) {
    const float* x   = (const float*)d_in[0];
    const float* W1  = (const float*)d_in[1];
    const float* b1  = (const float*)d_in[2];
    const float* W2  = (const float*)d_in[3];
    const float* b2  = (const float*)d_in[4];
    const float* W3  = (const float*)d_in[5];
    const float* b3  = (const float*)d_in[6];
    const float* Wl1 = (const float*)d_in[7];
    const float* bl1 = (const float*)d_in[8];
    const float* Wl2 = (const float*)d_in[9];
    const float* bl2 = (const float*)d_in[10];
    const int*   ei  = (const int*)d_in[11];
    const int*   bat = (const int*)d_in[12];

    const int N = in_sizes[0] / 128;
    const int E = in_sizes[11] / 2;
    const int G = out_size;  // [G,1]
    const int* src = ei;
    const int* dst = ei + E;

    const int nb = (N + DPB - 1) >> NB_SHIFT;            // buckets (782)
    const int avg = E / nb;
    const int cap = (avg + (avg >> 3) + 1024 + 255) & ~255;  // ~avg+13%+1K

    char* wsb = (char*)d_ws;
    size_t off = 0;
    auto alloc = [&](size_t bytes) {
        void* p = wsb + off;
        off += (bytes + 255) & ~(size_t)255;
        return p;
    };
    __half*   g      = (__half*)alloc((size_t)N * H96 * 2);
    __half*   h      = (__half*)alloc((size_t)N * H96 * 2);  // reused all layers
    int*      csr    = (int*)alloc((size_t)E * 4);
    int*      rowptr = (int*)alloc((size_t)(N + 1) * 4);
    float*    dinv   = (float*)alloc((size_t)N * 4);
    unsigned* pairs  = (unsigned*)alloc((size_t)nb * cap * 4);
    int*      gfill  = (int*)alloc((size_t)(nb + 1) * 4);
    int*      bstart = (int*)alloc((size_t)(nb + 1) * 4);

    hipMemsetAsync(gfill, 0, (size_t)nb * 4, stream);

    // CSR build: 2-level counting sort (R4)
    const int bs_blocks = (E + EPB - 1) / EPB;
    k_binscatter<<<bs_blocks, 256, 0, stream>>>(src, dst, E, nb, cap, gfill, pairs);
    k_bstart<<<1, 1024, 0, stream>>>(gfill, bstart, nb);
    k_build2<<<nb, 256, 0, stream>>>(pairs, gfill, bstart, cap, rowptr, dinv, csr, N, E);

    const int gemm_blocks = N / 64;          // 200000/64 = 3125
    const int agg_blocks = (N + 3) / 4;      // 4 nodes (waves) per 256-thr block

    // layer 1 (A = x in f32, cast in-register)
    k_gemm_mfma<128, float><<<gemm_blocks, 256, 0, stream>>>(x, W1, dinv, g);
    k_agg<<<agg_blocks, 256, 0, stream>>>(g, rowptr, csr, dinv, b1, h, N, 1);
    // layer 2 (A = h fp16)
    k_gemm_mfma<96, __half><<<gemm_blocks, 256, 0, stream>>>(h, W2, dinv, g);
    k_agg<<<agg_blocks, 256, 0, stream>>>(g, rowptr, csr, dinv, b2, h, N, 1);
    // layer 3
    k_gemm_mfma<96, __half><<<gemm_blocks, 256, 0, stream>>>(h, W3, dinv, g);
    k_agg<<<agg_blocks, 256, 0, stream>>>(g, rowptr, csr, dinv, b3, h, N, 0);

    // pool + head (reads fp16 h)
    k_pool_head<<<G, 128, 0, stream>>>(h, bat, Wl1, bl1, Wl2, bl2, (float*)d_out, N);
}